// Round 3
// baseline (2077.800 us; speedup 1.0000x reference)
//
#include <hip/hip_runtime.h>
#include <hip/hip_bf16.h>

// Persistent-kernel chain: 15 layers of 2048x2048 matvec in ONE regular
// launch. Grid = 256 blocks (one per CU) x 512 threads (8 waves) = 2048
// waves, one wave per output row. Per-layer grid barrier via agent-scope
// atomic counters in d_ws (release fetch_add by producers, relaxed spin +
// final acquire load by consumers). Next-layer W row is prefetched into
// registers before the dot so it stays in flight across the barrier spin.

#define NN 2048
#define NL 15
#define NWAVES 2048u

__device__ __forceinline__ void load_row(const float* W, int l, int row,
                                         int lane, float4* w) {
    const float4* Wr = reinterpret_cast<const float4*>(
        W + (size_t)l * NN * NN + (size_t)row * NN);
#pragma unroll
    for (int k = 0; k < 8; ++k) w[k] = Wr[lane + k * 64];
}

__global__ __launch_bounds__(512, 2) void nn_chain(
    const float* __restrict__ x, const float* __restrict__ W,
    const float* __restrict__ b, float* __restrict__ out,
    float* __restrict__ vbuf, unsigned int* __restrict__ cnt)
{
    const int lane = threadIdx.x & 63;
    const int wid  = threadIdx.x >> 6;
    const int row  = blockIdx.x * 8 + wid;   // 256 blocks * 8 waves = 2048 rows

    float4 wA[8], wB[8];
    load_row(W, 0, row, lane, wA);   // prologue: W[0] in flight

#pragma unroll
    for (int l = 0; l < NL; ++l) {
        float4* wcur = (l & 1) ? wB : wA;   // static after full unroll
        float4* wnxt = (l & 1) ? wA : wB;
        const float* vin = (l == 0) ? x : (vbuf + ((l - 1) & 1) * NN);

        if (l > 0) {
            // wait for all 2048 waves to finish layer l-1 (relaxed spin)
            while (__hip_atomic_load(&cnt[l - 1], __ATOMIC_RELAXED,
                                     __HIP_MEMORY_SCOPE_AGENT) < NWAVES)
                __builtin_amdgcn_s_sleep(2);
            // one acquire load synchronizes with all producers' releases
            (void)__hip_atomic_load(&cnt[l - 1], __ATOMIC_ACQUIRE,
                                    __HIP_MEMORY_SCOPE_AGENT);
        }

        // v loads FIRST (oldest in vmcnt order) ...
        const float4* v4 = reinterpret_cast<const float4*>(vin);
        float4 v[8];
#pragma unroll
        for (int k = 0; k < 8; ++k) v[k] = v4[lane + k * 64];

        // ... then next-layer W prefetch (newest): the dot below waits only
        // for v, leaving the prefetch in flight across the next barrier.
        if (l + 1 < NL) load_row(W, l + 1, row, lane, wnxt);

        float acc = 0.f;
#pragma unroll
        for (int k = 0; k < 8; ++k)
            acc += wcur[k].x * v[k].x + wcur[k].y * v[k].y
                 + wcur[k].z * v[k].z + wcur[k].w * v[k].w;

#pragma unroll
        for (int off = 32; off > 0; off >>= 1)
            acc += __shfl_down(acc, off);

        if (l == NL - 1) {
            if (lane == 0) out[row] = acc + b[l * NN + row];
        } else {
            if (lane == 0) {
                float z = acc + b[l * NN + row];
                vbuf[(l & 1) * NN + row] = z / (1.f + __expf(-z));  // silu
                // release: publishes the vbuf store, then signals done
                __hip_atomic_fetch_add(&cnt[l], 1u, __ATOMIC_RELEASE,
                                       __HIP_MEMORY_SCOPE_AGENT);
            }
        }
    }
}

extern "C" void kernel_launch(void* const* d_in, const int* in_sizes, int n_in,
                              void* d_out, int out_size, void* d_ws, size_t ws_size,
                              hipStream_t stream) {
    const float* x = (const float*)d_in[0];   // [2048]
    const float* W = (const float*)d_in[1];   // [15, 2048, 2048]
    const float* b = (const float*)d_in[2];   // [15, 2048]
    float* out = (float*)d_out;               // [2048]

    unsigned int* cnt = (unsigned int*)d_ws;              // 15 counters
    float* vbuf = (float*)((char*)d_ws + 256);            // ping-pong [2][2048]

    // zero the barrier counters every call (deterministic, capture-legal)
    hipMemsetAsync(d_ws, 0, 256, stream);

    nn_chain<<<dim3(256), dim3(512), 0, stream>>>(x, W, b, out, vbuf, cnt);
}

// Round 4
// 266.313 us; speedup vs baseline: 7.8021x; 7.8021x over previous
//
#include <hip/hip_runtime.h>
#include <hip/hip_bf16.h>

// Persistent-kernel chain: 15 layers of 2048x2048 matvec in ONE launch.
// 256 blocks x 576 threads = 9 waves/block: waves 0..7 compute one row each
// (256*8 = 2048 rows), wave 8 is a dedicated SYNC wave.
//
// Barrier design (the round-3 version lost 135us/layer to sync):
//  - one atomic add per BLOCK per layer (256, not 2048), counters padded 256B
//  - only the sync wave executes atomics/fences; its vmcnt is empty, so the
//    compiler's agent-scope release (buffer_wbl2) / acquire (buffer_inv)
//    sequences cost ~nothing and never drain compute waves' prefetch
//  - compute waves use raw s_barrier + counted "s_waitcnt vmcnt(8)":
//    vbuf store issued FIRST, then the 8-load W[l+1] prefetch, then wait
//    until <=8 outstanding (store acked into L2, prefetch still in flight).
//    The weight stream thus stays busy across the entire barrier.

#define NN 2048
#define NL 15
#define NBLK 256
#define CNT_STRIDE 64   // uints per counter slot = 256 B

__device__ __forceinline__ void load_row(const float* W, int l, int row,
                                         int lane, float4* w) {
    const float4* Wr = reinterpret_cast<const float4*>(
        W + (size_t)l * NN * NN + (size_t)row * NN);
#pragma unroll
    for (int k = 0; k < 8; ++k) w[k] = Wr[lane + k * 64];
}

__global__ __launch_bounds__(576) void nn_chain(
    const float* __restrict__ x, const float* __restrict__ W,
    const float* __restrict__ b, float* __restrict__ out,
    float* __restrict__ vbuf, unsigned int* __restrict__ cnt)
{
    const int tid  = threadIdx.x;
    const int lane = tid & 63;
    const int wid  = tid >> 6;            // 0..8
    const bool is_compute = (wid < 8);
    const int row  = blockIdx.x * 8 + wid; // compute waves only

    float4 wA[8], wB[8];
    if (is_compute) load_row(W, 0, row, lane, wA);  // W[0] in flight

#pragma unroll
    for (int l = 0; l < NL; ++l) {
        float4* wcur = (l & 1) ? wB : wA;   // static after full unroll
        float4* wnxt = (l & 1) ? wA : wB;

        if (is_compute) {
            const float* vin = (l == 0) ? x : (vbuf + ((l - 1) & 1) * NN);
            const float4* v4 = reinterpret_cast<const float4*>(vin);
            float4 v[8];
#pragma unroll
            for (int k = 0; k < 8; ++k) v[k] = v4[lane + k * 64];

            float acc = 0.f;
#pragma unroll
            for (int k = 0; k < 8; ++k)
                acc += wcur[k].x * v[k].x + wcur[k].y * v[k].y
                     + wcur[k].z * v[k].z + wcur[k].w * v[k].w;

#pragma unroll
            for (int off = 32; off > 0; off >>= 1)
                acc += __shfl_down(acc, off);

            if (l == NL - 1) {
                if (lane == 0) out[row] = acc + b[l * NN + row];
            } else {
                if (lane == 0) {
                    float z = acc + b[l * NN + row];
                    vbuf[(l & 1) * NN + row] = z / (1.f + __expf(-z)); // silu
                }
                // compiler fence: store stays BEFORE the prefetch below
                asm volatile("" ::: "memory");
                load_row(W, l + 1, row, lane, wnxt);   // 8 loads, newest
                // store (oldest of the 9) acked; 8 prefetch loads keep flying
                asm volatile("s_waitcnt vmcnt(8)" ::: "memory");
            }
        }

        if (l < NL - 1) {
            __builtin_amdgcn_s_barrier();   // arrival (raw: no vmcnt drain)
            if (wid == 8 && lane == 0) {
                // release: wbl2 flushes this block's vbuf stores to L3
                __hip_atomic_fetch_add(&cnt[l * CNT_STRIDE], 1u,
                                       __ATOMIC_RELEASE,
                                       __HIP_MEMORY_SCOPE_AGENT);
                while (__hip_atomic_load(&cnt[l * CNT_STRIDE],
                                         __ATOMIC_RELAXED,
                                         __HIP_MEMORY_SCOPE_AGENT) < NBLK)
                    __builtin_amdgcn_s_sleep(1);
                // acquire: buffer_inv so this CU reads fresh vbuf
                (void)__hip_atomic_load(&cnt[l * CNT_STRIDE],
                                        __ATOMIC_ACQUIRE,
                                        __HIP_MEMORY_SCOPE_AGENT);
            }
            __builtin_amdgcn_s_barrier();   // gate for layer l+1
            asm volatile("" ::: "memory");  // keep v loads after the gate
        }
    }
}

extern "C" void kernel_launch(void* const* d_in, const int* in_sizes, int n_in,
                              void* d_out, int out_size, void* d_ws, size_t ws_size,
                              hipStream_t stream) {
    const float* x = (const float*)d_in[0];   // [2048]
    const float* W = (const float*)d_in[1];   // [15, 2048, 2048]
    const float* b = (const float*)d_in[2];   // [15, 2048]
    float* out = (float*)d_out;               // [2048]

    unsigned int* cnt = (unsigned int*)d_ws;           // 15 padded counters
    float* vbuf = (float*)((char*)d_ws + 4096);        // ping-pong [2][2048]

    // zero the barrier counters every call (deterministic, capture-legal)
    hipMemsetAsync(d_ws, 0, NL * CNT_STRIDE * sizeof(unsigned int), stream);

    nn_chain<<<dim3(NBLK), dim3(576), 0, stream>>>(x, W, b, out, vbuf, cnt);
}

// Round 5
// 260.153 us; speedup vs baseline: 7.9868x; 1.0237x over previous
//
#include <hip/hip_runtime.h>
#include <hip/hip_bf16.h>

// Persistent-kernel chain: 15 layers of 2048x2048 matvec in ONE launch.
// 256 blocks x 576 threads = 9 waves/block: waves 0..7 compute one row each
// (256*8 = 2048 rows), wave 8 is a dedicated SYNC wave.
//
// Round-5 fix: round 4 came back with VGPR_Count=40 -> the compiler did NOT
// keep the W double-buffer in registers (parity-indexed arrays in a loop the
// compiler declined to fully unroll). Here every layer is TEXTUALLY unrolled
// with explicitly named wA/wB buffers and constant indices only, so the
// next-layer W row provably lives in VGPRs and its 8 loads stay in flight
// across the grid barrier (counted s_waitcnt vmcnt(8): vbuf store acked,
// prefetch still flying).

#define NN 2048
#define NL 15
#define NBLK 256
#define CNT_STRIDE 64   // uints per counter slot = 256 B

__device__ __forceinline__ void load_row(const float* W, int l, int row,
                                         int lane, float4* w) {
    const float4* Wr = reinterpret_cast<const float4*>(
        W + (size_t)l * NN * NN + (size_t)row * NN);
#pragma unroll
    for (int k = 0; k < 8; ++k) w[k] = Wr[lane + k * 64];
}

// One hidden layer: dot(WCUR, v) -> silu -> vbuf; prefetch W[L_+1] into WNXT;
// grid barrier (sync wave only touches atomics).
#define HIDDEN_LAYER(L_, WCUR, WNXT)                                         \
    {                                                                        \
        if (is_compute) {                                                    \
            const float* vin = ((L_) == 0) ? x : (vbuf + (((L_)-1) & 1) * NN); \
            const float4* v4 = reinterpret_cast<const float4*>(vin);         \
            float4 v[8];                                                     \
            _Pragma("unroll")                                                \
            for (int k = 0; k < 8; ++k) v[k] = v4[lane + k * 64];            \
            float acc = 0.f;                                                 \
            _Pragma("unroll")                                                \
            for (int k = 0; k < 8; ++k)                                      \
                acc += WCUR[k].x * v[k].x + WCUR[k].y * v[k].y               \
                     + WCUR[k].z * v[k].z + WCUR[k].w * v[k].w;              \
            _Pragma("unroll")                                                \
            for (int off = 32; off > 0; off >>= 1)                           \
                acc += __shfl_down(acc, off);                                \
            if (lane == 0) {                                                 \
                float z = acc + b[(L_) * NN + row];                          \
                vbuf[((L_) & 1) * NN + row] = z / (1.f + __expf(-z));        \
            }                                                                \
            asm volatile("" ::: "memory");  /* store before prefetch */      \
            load_row(W, (L_) + 1, row, lane, WNXT);                          \
            /* store (oldest) acked; 8 prefetch loads keep flying */         \
            asm volatile("s_waitcnt vmcnt(8)" ::: "memory");                 \
        }                                                                    \
        __builtin_amdgcn_s_barrier(); /* arrival (raw, no vmcnt drain) */    \
        if (wid == 8 && lane == 0) {                                         \
            __hip_atomic_fetch_add(&cnt[(L_) * CNT_STRIDE], 1u,              \
                                   __ATOMIC_RELEASE,                         \
                                   __HIP_MEMORY_SCOPE_AGENT);                \
            while (__hip_atomic_load(&cnt[(L_) * CNT_STRIDE],                \
                                     __ATOMIC_RELAXED,                       \
                                     __HIP_MEMORY_SCOPE_AGENT) < NBLK)       \
                __builtin_amdgcn_s_sleep(1);                                 \
            (void)__hip_atomic_load(&cnt[(L_) * CNT_STRIDE],                 \
                                    __ATOMIC_ACQUIRE,                        \
                                    __HIP_MEMORY_SCOPE_AGENT);               \
        }                                                                    \
        __builtin_amdgcn_s_barrier(); /* gate for layer L_+1 */              \
        asm volatile("" ::: "memory");                                       \
    }

__global__ __launch_bounds__(576) void nn_chain(
    const float* __restrict__ x, const float* __restrict__ W,
    const float* __restrict__ b, float* __restrict__ out,
    float* __restrict__ vbuf, unsigned int* __restrict__ cnt)
{
    const int tid  = threadIdx.x;
    const int lane = tid & 63;
    const int wid  = tid >> 6;            // 0..8
    const bool is_compute = (wid < 8);
    const int row  = blockIdx.x * 8 + wid; // compute waves only

    float4 wA[8], wB[8];
    if (is_compute) load_row(W, 0, row, lane, wA);  // W[0] in flight

    HIDDEN_LAYER(0,  wA, wB)
    HIDDEN_LAYER(1,  wB, wA)
    HIDDEN_LAYER(2,  wA, wB)
    HIDDEN_LAYER(3,  wB, wA)
    HIDDEN_LAYER(4,  wA, wB)
    HIDDEN_LAYER(5,  wB, wA)
    HIDDEN_LAYER(6,  wA, wB)
    HIDDEN_LAYER(7,  wB, wA)
    HIDDEN_LAYER(8,  wA, wB)
    HIDDEN_LAYER(9,  wB, wA)
    HIDDEN_LAYER(10, wA, wB)
    HIDDEN_LAYER(11, wB, wA)
    HIDDEN_LAYER(12, wA, wB)
    HIDDEN_LAYER(13, wB, wA)

    // Output layer 14: identity activation, write d_out. wcur = wA (14 even).
    if (is_compute) {
        const float4* v4 = reinterpret_cast<const float4*>(vbuf + (13 & 1) * NN);
        float4 v[8];
#pragma unroll
        for (int k = 0; k < 8; ++k) v[k] = v4[lane + k * 64];
        float acc = 0.f;
#pragma unroll
        for (int k = 0; k < 8; ++k)
            acc += wA[k].x * v[k].x + wA[k].y * v[k].y
                 + wA[k].z * v[k].z + wA[k].w * v[k].w;
#pragma unroll
        for (int off = 32; off > 0; off >>= 1)
            acc += __shfl_down(acc, off);
        if (lane == 0) out[row] = acc + b[14 * NN + row];
    }
}

extern "C" void kernel_launch(void* const* d_in, const int* in_sizes, int n_in,
                              void* d_out, int out_size, void* d_ws, size_t ws_size,
                              hipStream_t stream) {
    const float* x = (const float*)d_in[0];   // [2048]
    const float* W = (const float*)d_in[1];   // [15, 2048, 2048]
    const float* b = (const float*)d_in[2];   // [15, 2048]
    float* out = (float*)d_out;               // [2048]

    unsigned int* cnt = (unsigned int*)d_ws;           // 15 padded counters
    float* vbuf = (float*)((char*)d_ws + 4096);        // ping-pong [2][2048]

    // zero the barrier counters every call (deterministic, capture-legal)
    hipMemsetAsync(d_ws, 0, NL * CNT_STRIDE * sizeof(unsigned int), stream);

    nn_chain<<<dim3(NBLK), dim3(576), 0, stream>>>(x, W, b, out, vbuf, cnt);
}

// Round 7
// 175.515 us; speedup vs baseline: 11.8383x; 1.4822x over previous
//
#include <hip/hip_runtime.h>
#include <hip/hip_bf16.h>

// Persistent-kernel chain: 15 layers of 2048x2048 matvec in ONE launch.
// 256 blocks x 576 threads (9 waves): waves 0..7 compute one row each
// (256*8 = 2048 rows), wave 8 is a dedicated SYNC wave. 1 block/CU
// (LDS-bound) => co-residency structurally guaranteed.
//
// W is double-buffered in LDS via global_load_lds (async, vmcnt-counted,
// no VGPRs, cannot be sunk by the compiler). Each compute wave stages its
// own NEXT-layer row right after issuing its v loads; the staging ops are
// the newest vmcnt entries, so the compiler's counted waits for v leave
// them in flight across the dot + the entire barrier window.
//
// Sync (r4/r5-proven correctness shape, minus the costly RELEASE):
//  - compute waves hand z to the sync wave via LDS and never drain vmcnt
//  - sync wave: agent-scope relaxed atomic stores (sc1, write-through) +
//    s_waitcnt vmcnt(0) ack + relaxed fetch_add + relaxed spin + one
//    ACQUIRE load (buffer_inv: invalidates this CU's L1 + XCD L2, making
//    the next layer's plain cached v loads safe).

#define NN 2048
#define NL 15
#define NBLK 256
#define CNT_STRIDE 64   // uints per counter slot = 256 B

typedef const __attribute__((address_space(1))) unsigned int* gas1_t;
typedef __attribute__((address_space(3))) unsigned int* las3_t;

__global__ __launch_bounds__(576) void nn_chain(
    const float* __restrict__ x, const float* __restrict__ W,
    const float* __restrict__ b, float* __restrict__ out,
    float* __restrict__ vbuf, unsigned int* __restrict__ cnt)
{
    __shared__ float wt[2][8][NN];   // 128 KiB: [buf][wave-row][2048]
    __shared__ float lds_z[64];

    const int lane = threadIdx.x & 63;
    const int wid  = threadIdx.x >> 6;           // 0..8
    const bool is_compute = (wid < 8);
    const int row  = blockIdx.x * 8 + wid;       // compute waves only

    // prologue: stage W[0] rows into wt[0]
    if (is_compute) {
        const float* src = W + (size_t)row * NN;
#pragma unroll
        for (int k = 0; k < 8; ++k)
            __builtin_amdgcn_global_load_lds(
                (gas1_t)(src + k * 256 + lane * 4),
                (las3_t)(&wt[0][wid][k * 256]), 16, 0, 0);
    }

#pragma unroll
    for (int l = 0; l < NL; ++l) {
        const int cur = l & 1;
        if (is_compute) {
            // staging of W[l] complete (issued a full layer ago)
            asm volatile("s_waitcnt vmcnt(0)" ::: "memory");
            __builtin_amdgcn_sched_barrier(0);

            // v loads FIRST (oldest in vmcnt order; plain cached float4 —
            // legal because the sync wave's ACQUIRE invalidated L1/L2)
            const float* vin = (l == 0) ? x : (vbuf + ((l + 1) & 1) * NN);
            const float4* v4 = reinterpret_cast<const float4*>(vin);
            float4 v[8];
#pragma unroll
            for (int k = 0; k < 8; ++k) v[k] = v4[lane + k * 64];

            asm volatile("" ::: "memory");  // keep staging AFTER v loads

            // stage W[l+1] (newest vmcnt entries; fly across the barrier)
            if (l + 1 < NL) {
                const float* src =
                    W + (size_t)(l + 1) * NN * NN + (size_t)row * NN;
#pragma unroll
                for (int k = 0; k < 8; ++k)
                    __builtin_amdgcn_global_load_lds(
                        (gas1_t)(src + k * 256 + lane * 4),
                        (las3_t)(&wt[cur ^ 1][wid][k * 256]), 16, 0, 0);
            }

            // dot: W row from LDS (conflict-free b128), v from registers
            float acc = 0.f;
#pragma unroll
            for (int k = 0; k < 8; ++k) {
                float4 wv = *reinterpret_cast<const float4*>(
                    &wt[cur][wid][lane * 4 + k * 256]);
                acc += wv.x * v[k].x + wv.y * v[k].y
                     + wv.z * v[k].z + wv.w * v[k].w;
            }
#pragma unroll
            for (int o = 32; o > 0; o >>= 1) acc += __shfl_down(acc, o);

            if (l == NL - 1) {
                if (lane == 0) out[row] = acc + b[l * NN + row];
            } else if (lane == 0) {
                float z = acc + b[l * NN + row];
                lds_z[wid] = z / (1.f + __expf(-z));   // silu
            }
            asm volatile("s_waitcnt lgkmcnt(0)" ::: "memory");
        }

        if (l < NL - 1) {
            __builtin_amdgcn_s_barrier();   // arrival (raw: no vmcnt drain)
            if (wid == 8) {
                float z = lds_z[lane & 7];
                if (lane < 8)   // agent-scope store: sc1 write-through to L3
                    __hip_atomic_store(vbuf + cur * NN + blockIdx.x * 8 + lane,
                                       z, __ATOMIC_RELAXED,
                                       __HIP_MEMORY_SCOPE_AGENT);
                // ack: this wave's only vmem — stores visible at L3
                asm volatile("s_waitcnt vmcnt(0)" ::: "memory");
                if (lane == 0) {
                    __hip_atomic_fetch_add(&cnt[l * CNT_STRIDE], 1u,
                                           __ATOMIC_RELAXED,
                                           __HIP_MEMORY_SCOPE_AGENT);
                    while (__hip_atomic_load(&cnt[l * CNT_STRIDE],
                                             __ATOMIC_RELAXED,
                                             __HIP_MEMORY_SCOPE_AGENT) < NBLK)
                        __builtin_amdgcn_s_sleep(2);
                    // acquire: buffer_inv -> this CU's L1 + XCD L2 fresh
                    (void)__hip_atomic_load(&cnt[l * CNT_STRIDE],
                                            __ATOMIC_ACQUIRE,
                                            __HIP_MEMORY_SCOPE_AGENT);
                }
            }
            __builtin_amdgcn_s_barrier();   // gate for layer l+1
            asm volatile("" ::: "memory");  // keep next v loads after gate
        }
    }
}

extern "C" void kernel_launch(void* const* d_in, const int* in_sizes, int n_in,
                              void* d_out, int out_size, void* d_ws, size_t ws_size,
                              hipStream_t stream) {
    const float* x = (const float*)d_in[0];   // [2048]
    const float* W = (const float*)d_in[1];   // [15, 2048, 2048]
    const float* b = (const float*)d_in[2];   // [15, 2048]
    float* out = (float*)d_out;               // [2048]

    unsigned int* cnt = (unsigned int*)d_ws;           // 14 padded counters
    float* vbuf = (float*)((char*)d_ws + 4096);        // ping-pong [2][2048]

    // zero the barrier counters every call (deterministic, capture-legal)
    hipMemsetAsync(d_ws, 0, 4096, stream);

    nn_chain<<<dim3(NBLK), dim3(576), 0, stream>>>(x, W, b, out, vbuf, cnt);
}

// Round 8
// 165.289 us; speedup vs baseline: 12.5707x; 1.0619x over previous
//
#include <hip/hip_runtime.h>
#include <hip/hip_bf16.h>

// Persistent-kernel chain: 15 layers of 2048x2048 matvec in ONE launch.
// 256 blocks x 576 threads (9 waves): waves 0..7 compute one row each
// (256*8 = 2048 rows), wave 8 is a dedicated SYNC wave. 1 block/CU.
//
// ZERO cache-maintenance design (r3/r4/r7 post-mortems: acquire/release
// ops serialize ~0.4us each at the shared per-XCD L2 and were the entire
// 13-135 us/layer sync cost):
//  - W (read-only): plain cached global_load_lds double-buffer staging;
//    issued right after the v loads, in flight across the whole barrier.
//  - activations (cross-XCD): producers store via agent-relaxed atomic
//    (sc-flagged write-through to L3) + vmcnt(0) ack; consumers read via
//    agent-relaxed atomic 8B loads (bypass L1/L2, hit L3 directly).
//    => no buffer_inv / buffer_wbl2 anywhere in the kernel.
//  - barrier: 1 relaxed fetch_add + relaxed spin per block (sync wave).

#define NN 2048
#define NL 15
#define NBLK 256
#define CNT_STRIDE 64   // uints per counter slot = 256 B

typedef const __attribute__((address_space(1))) unsigned int* gas1_t;
typedef __attribute__((address_space(3))) unsigned int* las3_t;

__global__ __launch_bounds__(576) void nn_chain(
    const float* __restrict__ x, const float* __restrict__ W,
    const float* __restrict__ b, float* __restrict__ out,
    float* __restrict__ vbuf, unsigned int* __restrict__ cnt)
{
    __shared__ float wt[2][8][NN];   // 128 KiB: [buf][wave-row][2048]
    __shared__ float lds_z[64];

    const int lane = threadIdx.x & 63;
    const int wid  = threadIdx.x >> 6;           // 0..8
    const bool is_compute = (wid < 8);
    const int row  = blockIdx.x * 8 + wid;       // compute waves only

    // prologue: stage W[0] rows into wt[0]
    if (is_compute) {
        const float* src = W + (size_t)row * NN;
#pragma unroll
        for (int k = 0; k < 8; ++k)
            __builtin_amdgcn_global_load_lds(
                (gas1_t)(src + k * 256 + lane * 4),
                (las3_t)(&wt[0][wid][k * 256]), 16, 0, 0);
    }

#pragma unroll
    for (int l = 0; l < NL; ++l) {
        const int cur = l & 1;
        if (is_compute) {
            // staging of W[l] complete (issued a full layer ago)
            asm volatile("s_waitcnt vmcnt(0)" ::: "memory");
            __builtin_amdgcn_sched_barrier(0);

            // v loads FIRST (oldest in vmcnt order). Coherent 8B atomic
            // loads bypass stale L1/L2 and read the L3 coherence point.
            float4 v[8];
            if (l == 0) {
                const float4* v4 = reinterpret_cast<const float4*>(x);
#pragma unroll
                for (int k = 0; k < 8; ++k) v[k] = v4[lane + k * 64];
            } else {
                const unsigned long long* vq =
                    reinterpret_cast<const unsigned long long*>(
                        vbuf + ((l + 1) & 1) * NN);
#pragma unroll
                for (int k = 0; k < 8; ++k) {
                    unsigned long long q0 = __hip_atomic_load(
                        vq + 2 * lane + k * 128, __ATOMIC_RELAXED,
                        __HIP_MEMORY_SCOPE_AGENT);
                    unsigned long long q1 = __hip_atomic_load(
                        vq + 2 * lane + 1 + k * 128, __ATOMIC_RELAXED,
                        __HIP_MEMORY_SCOPE_AGENT);
                    float2 a = __builtin_bit_cast(float2, q0);
                    float2 c = __builtin_bit_cast(float2, q1);
                    v[k] = make_float4(a.x, a.y, c.x, c.y);
                }
            }

            asm volatile("" ::: "memory");  // keep staging AFTER v loads

            // stage W[l+1] (newest vmcnt entries; fly across the barrier)
            if (l + 1 < NL) {
                const float* src =
                    W + (size_t)(l + 1) * NN * NN + (size_t)row * NN;
#pragma unroll
                for (int k = 0; k < 8; ++k)
                    __builtin_amdgcn_global_load_lds(
                        (gas1_t)(src + k * 256 + lane * 4),
                        (las3_t)(&wt[cur ^ 1][wid][k * 256]), 16, 0, 0);
            }

            // dot: W row from LDS (b128), v from registers
            float acc = 0.f;
#pragma unroll
            for (int k = 0; k < 8; ++k) {
                float4 wv = *reinterpret_cast<const float4*>(
                    &wt[cur][wid][lane * 4 + k * 256]);
                acc += wv.x * v[k].x + wv.y * v[k].y
                     + wv.z * v[k].z + wv.w * v[k].w;
            }
#pragma unroll
            for (int o = 32; o > 0; o >>= 1) acc += __shfl_down(acc, o);

            if (l == NL - 1) {
                if (lane == 0) out[row] = acc + b[l * NN + row];
            } else if (lane == 0) {
                float z = acc + b[l * NN + row];
                lds_z[wid] = z / (1.f + __expf(-z));   // silu
            }
            asm volatile("s_waitcnt lgkmcnt(0)" ::: "memory");
        }

        if (l < NL - 1) {
            __builtin_amdgcn_s_barrier();   // arrival (raw: no vmcnt drain)
            if (wid == 8) {
                float z = lds_z[lane & 7];
                if (lane < 8)   // coherent write-through to L3, no fence
                    __hip_atomic_store(vbuf + cur * NN + blockIdx.x * 8 + lane,
                                       z, __ATOMIC_RELAXED,
                                       __HIP_MEMORY_SCOPE_AGENT);
                // ack: this wave's only vmem — stores visible at L3
                asm volatile("s_waitcnt vmcnt(0)" ::: "memory");
                if (lane == 0) {
                    __hip_atomic_fetch_add(&cnt[l * CNT_STRIDE], 1u,
                                           __ATOMIC_RELAXED,
                                           __HIP_MEMORY_SCOPE_AGENT);
                    while (__hip_atomic_load(&cnt[l * CNT_STRIDE],
                                             __ATOMIC_RELAXED,
                                             __HIP_MEMORY_SCOPE_AGENT) < NBLK)
                        __builtin_amdgcn_s_sleep(2);
                    // NO acquire here — consumers' loads are coherent.
                }
            }
            __builtin_amdgcn_s_barrier();   // gate for layer l+1
            asm volatile("" ::: "memory");  // keep next v loads after gate
        }
    }
}

extern "C" void kernel_launch(void* const* d_in, const int* in_sizes, int n_in,
                              void* d_out, int out_size, void* d_ws, size_t ws_size,
                              hipStream_t stream) {
    const float* x = (const float*)d_in[0];   // [2048]
    const float* W = (const float*)d_in[1];   // [15, 2048, 2048]
    const float* b = (const float*)d_in[2];   // [15, 2048]
    float* out = (float*)d_out;               // [2048]

    unsigned int* cnt = (unsigned int*)d_ws;           // 14 padded counters
    float* vbuf = (float*)((char*)d_ws + 4096);        // ping-pong [2][2048]

    // zero the barrier counters every call (deterministic, capture-legal)
    hipMemsetAsync(d_ws, 0, 4096, stream);

    nn_chain<<<dim3(NBLK), dim3(576), 0, stream>>>(x, W, b, out, vbuf, cnt);
}

// Round 9
// 125.757 us; speedup vs baseline: 16.5224x; 1.3144x over previous
//
#include <hip/hip_runtime.h>
#include <hip/hip_bf16.h>

// Persistent-kernel chain: 15 layers of 2048x2048 matvec in ONE launch.
// 256 blocks x 576 threads (9 waves): waves 0..7 compute one row each
// (256*8 = 2048 rows), wave 8 is a dedicated SYNC wave. 1 block/CU.
//
// Grid barrier with ZERO same-address RMWs (r3/r4/r8 post-mortems fit
// ~110cy per serialized same-address atomic RMW at L3: 2048 RMW=135us/L,
// 256 RMW=13.5us/L). Design:
//  - each block's sync wave WRITES its own flag slot flags[b] = l+1
//    (monotone tag, no re-zero) after its z-store ack (vmcnt(0)).
//    256 independent stores to distinct addresses: fully parallel.
//  - every sync wave POLLS all 256 flags (64 lanes x 16B coherent loads)
//    until __all(flags >= l+1). No RMW anywhere.
//  - activations cross XCDs via agent-relaxed atomics (L3 coherence
//    point): producers store z (sc-flagged) + vmcnt ack; consumers do
//    relaxed 8B atomic loads. No buffer_inv / buffer_wbl2 anywhere.
//  - W (read-only): plain cached global_load_lds double-buffer staging,
//    issued after the v loads, in flight across the whole barrier.

#define NN 2048
#define NL 15
#define NBLK 256

typedef const __attribute__((address_space(1))) unsigned int* gas1_t;
typedef __attribute__((address_space(3))) unsigned int* las3_t;

__global__ __launch_bounds__(576) void nn_chain(
    const float* __restrict__ x, const float* __restrict__ W,
    const float* __restrict__ b, float* __restrict__ out,
    float* __restrict__ vbuf, unsigned int* __restrict__ flags)
{
    __shared__ float wt[2][8][NN];   // 128 KiB: [buf][wave-row][2048]
    __shared__ float lds_z[64];

    const int lane = threadIdx.x & 63;
    const int wid  = threadIdx.x >> 6;           // 0..8
    const bool is_compute = (wid < 8);
    const int row  = blockIdx.x * 8 + wid;       // compute waves only

    // prologue: stage W[0] rows into wt[0]
    if (is_compute) {
        const float* src = W + (size_t)row * NN;
#pragma unroll
        for (int k = 0; k < 8; ++k)
            __builtin_amdgcn_global_load_lds(
                (gas1_t)(src + k * 256 + lane * 4),
                (las3_t)(&wt[0][wid][k * 256]), 16, 0, 0);
    }

#pragma unroll
    for (int l = 0; l < NL; ++l) {
        const int cur = l & 1;
        if (is_compute) {
            // staging of W[l] complete (issued a full layer ago)
            asm volatile("s_waitcnt vmcnt(0)" ::: "memory");
            __builtin_amdgcn_sched_barrier(0);

            // v loads FIRST (oldest in vmcnt order). Coherent 8B atomic
            // loads bypass stale L1/L2 and read the L3 coherence point.
            float4 v[8];
            if (l == 0) {
                const float4* v4 = reinterpret_cast<const float4*>(x);
#pragma unroll
                for (int k = 0; k < 8; ++k) v[k] = v4[lane + k * 64];
            } else {
                const unsigned long long* vq =
                    reinterpret_cast<const unsigned long long*>(
                        vbuf + ((l + 1) & 1) * NN);
#pragma unroll
                for (int k = 0; k < 8; ++k) {
                    unsigned long long q0 = __hip_atomic_load(
                        vq + 2 * lane + k * 128, __ATOMIC_RELAXED,
                        __HIP_MEMORY_SCOPE_AGENT);
                    unsigned long long q1 = __hip_atomic_load(
                        vq + 2 * lane + 1 + k * 128, __ATOMIC_RELAXED,
                        __HIP_MEMORY_SCOPE_AGENT);
                    float2 a = __builtin_bit_cast(float2, q0);
                    float2 c = __builtin_bit_cast(float2, q1);
                    v[k] = make_float4(a.x, a.y, c.x, c.y);
                }
            }

            asm volatile("" ::: "memory");  // keep staging AFTER v loads

            // stage W[l+1] (newest vmcnt entries; fly across the barrier)
            if (l + 1 < NL) {
                const float* src =
                    W + (size_t)(l + 1) * NN * NN + (size_t)row * NN;
#pragma unroll
                for (int k = 0; k < 8; ++k)
                    __builtin_amdgcn_global_load_lds(
                        (gas1_t)(src + k * 256 + lane * 4),
                        (las3_t)(&wt[cur ^ 1][wid][k * 256]), 16, 0, 0);
            }

            // dot: W row from LDS (b128), v from registers
            float acc = 0.f;
#pragma unroll
            for (int k = 0; k < 8; ++k) {
                float4 wv = *reinterpret_cast<const float4*>(
                    &wt[cur][wid][lane * 4 + k * 256]);
                acc += wv.x * v[k].x + wv.y * v[k].y
                     + wv.z * v[k].z + wv.w * v[k].w;
            }
#pragma unroll
            for (int o = 32; o > 0; o >>= 1) acc += __shfl_down(acc, o);

            if (l == NL - 1) {
                if (lane == 0) out[row] = acc + b[l * NN + row];
            } else if (lane == 0) {
                float z = acc + b[l * NN + row];
                lds_z[wid] = z / (1.f + __expf(-z));   // silu
            }
            asm volatile("s_waitcnt lgkmcnt(0)" ::: "memory");
        }

        if (l < NL - 1) {
            __builtin_amdgcn_s_barrier();   // arrival (raw: no vmcnt drain)
            if (wid == 8) {
                const unsigned int tag = (unsigned int)(l + 1);
                float z = lds_z[lane & 7];
                if (lane < 8)   // coherent write-through to L3, no fence
                    __hip_atomic_store(vbuf + cur * NN + blockIdx.x * 8 + lane,
                                       z, __ATOMIC_RELAXED,
                                       __HIP_MEMORY_SCOPE_AGENT);
                // ack: this wave's only vmem — z stores visible at L3
                asm volatile("s_waitcnt vmcnt(0)" ::: "memory");
                // publish arrival: own flag slot, no RMW
                __hip_atomic_store(&flags[blockIdx.x], tag, __ATOMIC_RELAXED,
                                   __HIP_MEMORY_SCOPE_AGENT);
                // all-to-all poll: 64 lanes x 4 flags = 256
                const unsigned long long* fq =
                    reinterpret_cast<const unsigned long long*>(flags);
                for (;;) {
                    unsigned long long q0 = __hip_atomic_load(
                        fq + 2 * lane, __ATOMIC_RELAXED,
                        __HIP_MEMORY_SCOPE_AGENT);
                    unsigned long long q1 = __hip_atomic_load(
                        fq + 2 * lane + 1, __ATOMIC_RELAXED,
                        __HIP_MEMORY_SCOPE_AGENT);
                    unsigned int f0 = (unsigned int)q0;
                    unsigned int f1 = (unsigned int)(q0 >> 32);
                    unsigned int f2 = (unsigned int)q1;
                    unsigned int f3 = (unsigned int)(q1 >> 32);
                    if (__all(f0 >= tag && f1 >= tag &&
                              f2 >= tag && f3 >= tag))
                        break;
                    __builtin_amdgcn_s_sleep(1);
                }
            }
            __builtin_amdgcn_s_barrier();   // gate for layer l+1
            asm volatile("" ::: "memory");  // keep next v loads after gate
        }
    }
}

extern "C" void kernel_launch(void* const* d_in, const int* in_sizes, int n_in,
                              void* d_out, int out_size, void* d_ws, size_t ws_size,
                              hipStream_t stream) {
    const float* x = (const float*)d_in[0];   // [2048]
    const float* W = (const float*)d_in[1];   // [15, 2048, 2048]
    const float* b = (const float*)d_in[2];   // [15, 2048]
    float* out = (float*)d_out;               // [2048]

    unsigned int* flags = (unsigned int*)d_ws;         // [256] arrival tags
    float* vbuf = (float*)((char*)d_ws + 4096);        // ping-pong [2][2048]

    // zero flags every call (deterministic, capture-legal)
    hipMemsetAsync(d_ws, 0, 4096, stream);

    nn_chain<<<dim3(NBLK), dim3(576), 0, stream>>>(x, W, b, out, vbuf, flags);
}